// Round 1
// baseline (132.861 us; speedup 1.0000x reference)
//
#include <hip/hip_runtime.h>
#include <hip/hip_fp16.h>

typedef _Float16 half8v __attribute__((ext_vector_type(8)));
typedef _Float16 half2v __attribute__((ext_vector_type(2)));
typedef float f32x4 __attribute__((ext_vector_type(4)));

// DPP butterfly-add over 16-lane groups (pure VALU, no LDS traffic).
#define DPP_XADD(x, ctrl)                                                          \
  x += __builtin_bit_cast(float, __builtin_amdgcn_mov_dpp(                         \
           __builtin_bit_cast(int, x), ctrl, 0xf, 0xf, true))

// ---------------- prep kernel: fragment-ordered W/pvec (fp16) + pair table ----
// ws layout: [0,8192)  W frags  : half wf[ks(2)][nt(4)][lane(64)][j(8)]
//            [8192,10240) pvec frags: half pf[ks(2)][lane(64)][j(8)] (col 0 only)
//            [10240,11808) pair table: ushort tbl[780] = (ri<<8)|ci
__global__ void afm_prep(const float* __restrict__ W, const float* __restrict__ pvec,
                         unsigned char* __restrict__ ws) {
  const int tid = threadIdx.x;
  _Float16* wf = (_Float16*)ws;
  _Float16* pf = (_Float16*)(ws + 8192);
  unsigned short* tbl = (unsigned short*)(ws + 10240);
  for (int idx = tid; idx < 4096; idx += 256) {
    int j = idx & 7, lane = (idx >> 3) & 63, nt = (idx >> 9) & 3, ks = idx >> 11;
    int k = ks * 32 + (lane >> 4) * 8 + j;   // e index
    int u = nt * 16 + (lane & 15);           // u index
    wf[idx] = (_Float16)W[k * 64 + u];
  }
  for (int idx = tid; idx < 1024; idx += 256) {
    int j = idx & 7, lane = (idx >> 3) & 63, ks = idx >> 9;
    int k = ks * 32 + (lane >> 4) * 8 + j;
    pf[idx] = ((lane & 15) == 0) ? (_Float16)pvec[k] : (_Float16)0.f;
  }
  for (int p = tid; p < 780; p += 256) {
    int i = 0, rem = p;
    while (rem >= 39 - i) { rem -= 39 - i; ++i; }
    int j = i + 1 + rem;
    tbl[p] = (unsigned short)((i << 8) | j);
  }
}

// ---------------- main kernel: one block per batch row -----------------------
__global__ __launch_bounds__(256) void afm_main(
    const float* __restrict__ x, const float* __restrict__ bvec,
    const float* __restrict__ hvec, const unsigned char* __restrict__ ws,
    float* __restrict__ out) {
  __shared__ __align__(16) _Float16 xh[40 * 72];   // padded stride 72 halves (144B)
  __shared__ __align__(16) unsigned short tbls[784];
  __shared__ float scs[784];
  __shared__ float s2s[784];
  __shared__ float red[12];

  const int tid = threadIdx.x;
  const int b = blockIdx.x;
  const int lane = tid & 63;
  const int wid = tid >> 6;

  // ---- stage x[b] (40x64 fp32) -> LDS fp16, padded rows ----
  const float4* xg = (const float4*)(x + b * 2560);
#pragma unroll
  for (int it = 0; it < 3; ++it) {
    int g = tid + it * 256;
    if (g < 640) {
      float4 v = xg[g];
      int f = g >> 4, e4 = g & 15;
      half2v* dst = (half2v*)&xh[f * 72 + e4 * 4];
      dst[0] = __builtin_bit_cast(half2v, __builtin_amdgcn_cvt_pkrtz(v.x, v.y));
      dst[1] = __builtin_bit_cast(half2v, __builtin_amdgcn_cvt_pkrtz(v.z, v.w));
    }
  }
  // ---- stage pair table ----
  {
    const float4* tg = (const float4*)(ws + 10240);
    float4* ts = (float4*)tbls;
    if (tid < 98) ts[tid] = tg[tid];
  }
  // ---- per-lane fragments (coalesced, L1-hot) ----
  const half8v* wfg = (const half8v*)ws;
  half8v wf[2][4];
#pragma unroll
  for (int ks = 0; ks < 2; ++ks)
#pragma unroll
    for (int nt = 0; nt < 4; ++nt) wf[ks][nt] = wfg[(ks * 4 + nt) * 64 + lane];
  const half8v* pfg = (const half8v*)(ws + 8192);
  half8v pf[2] = {pfg[lane], pfg[64 + lane]};
  float bu[4], hu[4];
#pragma unroll
  for (int nt = 0; nt < 4; ++nt) {
    int u = nt * 16 + (lane & 15);
    bu[nt] = bvec[u];
    hu[nt] = hvec[u];
  }
  __syncthreads();

  // ---- phase A: per 16-pair M-tile, MFMA v = ip@W (+bias) and s2 = ip@pvec ----
  const int m = lane & 15, kg = lane >> 4;
  for (int t = wid; t < 49; t += 4) {
    int p = 16 * t + m;
    p = p > 779 ? 779 : p;           // clamp tail (writes masked below)
    unsigned pk = tbls[p];
    const _Float16* xi = &xh[(pk >> 8) * 72 + kg * 8];
    const _Float16* xj = &xh[(pk & 255) * 72 + kg * 8];
    half8v a0 = *(const half8v*)xi * *(const half8v*)xj;              // e = kg*8+j
    half8v a1 = *(const half8v*)(xi + 32) * *(const half8v*)(xj + 32); // e = 32+kg*8+j
    f32x4 acc[4], accp;
#pragma unroll
    for (int nt = 0; nt < 4; ++nt) acc[nt] = (f32x4){bu[nt], bu[nt], bu[nt], bu[nt]};
    accp = (f32x4){0.f, 0.f, 0.f, 0.f};
#pragma unroll
    for (int nt = 0; nt < 4; ++nt) {
      acc[nt] = __builtin_amdgcn_mfma_f32_16x16x32_f16(a0, wf[0][nt], acc[nt], 0, 0, 0);
      acc[nt] = __builtin_amdgcn_mfma_f32_16x16x32_f16(a1, wf[1][nt], acc[nt], 0, 0, 0);
    }
    accp = __builtin_amdgcn_mfma_f32_16x16x32_f16(a0, pf[0], accp, 0, 0, 0);
    accp = __builtin_amdgcn_mfma_f32_16x16x32_f16(a1, pf[1], accp, 0, 0, 0);
    // epilogue: score[p] = sum_u relu(v+b)*h[u]; C layout: col=lane&15, row=kg*4+r
#pragma unroll
    for (int r = 0; r < 4; ++r) {
      float s = fmaxf(acc[0][r], 0.f) * hu[0] + fmaxf(acc[1][r], 0.f) * hu[1] +
                fmaxf(acc[2][r], 0.f) * hu[2] + fmaxf(acc[3][r], 0.f) * hu[3];
      DPP_XADD(s, 0xB1);   // quad swap adjacent
      DPP_XADD(s, 0x4E);   // quad swap pairs
      DPP_XADD(s, 0x141);  // row half mirror
      DPP_XADD(s, 0x140);  // row mirror -> full 16-lane sum
      int pr = 16 * t + kg * 4 + r;
      if (m == 0 && pr < 780) {
        scs[pr] = s;
        s2s[pr] = accp[r];  // col 0 of pvec-MFMA = ip . pvec
      }
    }
  }
  __syncthreads();

  // ---- phase B: softmax over 780 + weighted sum of s2 ----
  float mx = -1e30f;
#pragma unroll
  for (int k2 = 0; k2 < 4; ++k2) {
    int p = tid + k2 * 256;
    if (p < 780) mx = fmaxf(mx, scs[p]);
  }
#pragma unroll
  for (int off = 32; off; off >>= 1) mx = fmaxf(mx, __shfl_xor(mx, off));
  if (lane == 0) red[wid] = mx;
  __syncthreads();
  mx = fmaxf(fmaxf(red[0], red[1]), fmaxf(red[2], red[3]));
  float num = 0.f, den = 0.f;
#pragma unroll
  for (int k2 = 0; k2 < 4; ++k2) {
    int p = tid + k2 * 256;
    if (p < 780) {
      float e = __expf(scs[p] - mx);
      num += e * s2s[p];
      den += e;
    }
  }
#pragma unroll
  for (int off = 32; off; off >>= 1) {
    num += __shfl_xor(num, off);
    den += __shfl_xor(den, off);
  }
  if (lane == 0) { red[4 + wid] = num; red[8 + wid] = den; }
  __syncthreads();
  if (tid == 0)
    out[b] = (red[4] + red[5] + red[6] + red[7]) /
             (red[8] + red[9] + red[10] + red[11]);
}

extern "C" void kernel_launch(void* const* d_in, const int* in_sizes, int n_in,
                              void* d_out, int out_size, void* d_ws, size_t ws_size,
                              hipStream_t stream) {
  const float* x    = (const float*)d_in[0];  // [4096,40,64]
  const float* W    = (const float*)d_in[1];  // [64,64]
  const float* bvec = (const float*)d_in[2];  // [64]
  const float* hvec = (const float*)d_in[3];  // [64,1]
  const float* pvec = (const float*)d_in[4];  // [64,1]
  float* out = (float*)d_out;                 // [4096,1]
  unsigned char* ws = (unsigned char*)d_ws;   // needs ~11.8 KB

  hipLaunchKernelGGL(afm_prep, dim3(1), dim3(256), 0, stream, W, pvec, ws);
  hipLaunchKernelGGL(afm_main, dim3(4096), dim3(256), 0, stream, x, bvec, hvec, ws, out);
}